// Round 1
// baseline (2277.512 us; speedup 1.0000x reference)
//
#include <hip/hip_runtime.h>
#include <math.h>

typedef _Float16 half8 __attribute__((ext_vector_type(8)));
typedef _Float16 half4v __attribute__((ext_vector_type(4)));
typedef float floatx16 __attribute__((ext_vector_type(16)));

#define TT 20
#define NB 64      // batch per step
#define LL 90
#define DD 64
#define RR 5760    // L*D
#define HH 1024
#define NG 4096    // 4*H
#define MM 1024

__device__ __forceinline__ float sigm(float x) { return 1.f / (1.f + expf(-x)); }

// ---------------- fp32 -> fp16 convert ----------------
__global__ __launch_bounds__(256) void k_conv(const float* __restrict__ s,
                                              _Float16* __restrict__ d, int n) {
    int i = (blockIdx.x * 256 + threadIdx.x) * 4;
    if (i + 4 <= n) {
        const float4 v = *(const float4*)(s + i);
        half4v o;
        o[0] = (_Float16)v.x; o[1] = (_Float16)v.y;
        o[2] = (_Float16)v.z; o[3] = (_Float16)v.w;
        *(half4v*)(d + i) = o;
    } else {
        for (; i < n; ++i) d[i] = (_Float16)s[i];
    }
}

// ---------------- xproj = feature @ attn_Wx  -> fp16 [1280][90][64] ----------------
__global__ __launch_bounds__(256) void k_xproj(const float* __restrict__ feat,
                                               const float* __restrict__ Wx,
                                               _Float16* __restrict__ xp) {
    __shared__ float sWx[DD * DD];
    __shared__ float sx[16 * DD];
    const int row = blockIdx.x;            // 0..1279  (= b*TT + t)
    const int tid = threadIdx.x;
    for (int e = tid * 4; e < DD * DD; e += 1024)
        *(float4*)(sWx + e) = *(const float4*)(Wx + e);
    const int a4 = tid & 15, lg = tid >> 4;
    const float* frow = feat + (size_t)row * RR;
    for (int lb = 0; lb < LL; lb += 16) {
        __syncthreads();
        { int e = tid * 4; int ls = e >> 6, dd = e & 63;
          if (lb + ls < LL) *(float4*)(sx + e) = *(const float4*)(frow + (lb + ls) * DD + dd); }
        __syncthreads();
        const int l = lb + lg;
        if (l < LL) {
            float a0 = 0, a1 = 0, a2 = 0, a3 = 0;
            for (int dd = 0; dd < DD; ++dd) {
                const float xv = sx[lg * DD + dd];
                const float4 wv = *(const float4*)(sWx + dd * DD + a4 * 4);
                a0 += xv * wv.x; a1 += xv * wv.y; a2 += xv * wv.z; a3 += xv * wv.w;
            }
            half4v o;
            o[0] = (_Float16)a0; o[1] = (_Float16)a1; o[2] = (_Float16)a2; o[3] = (_Float16)a3;
            *(half4v*)(xp + (size_t)row * RR + l * DD + a4 * 4) = o;
        }
    }
}

// ---------------- init h0, c0 ----------------
__global__ __launch_bounds__(256) void k_init(const float* __restrict__ feat,
        const float* __restrict__ iWh_w, const float* __restrict__ iWh_b,
        const float* __restrict__ iWc_w, const float* __restrict__ iWc_b,
        float* __restrict__ h, float* __restrict__ c, _Float16* __restrict__ h16) {
    __shared__ float f0p[4][DD];
    __shared__ float f0[DD];
    const int b = blockIdx.x, tid = threadIdx.x;
    const int dd = tid & 63, lg = tid >> 6;
    const float* frow = feat + (size_t)(b * TT) * RR;   // t = 0
    float p = 0;
    for (int l = lg; l < LL; l += 4) p += frow[l * DD + dd];
    f0p[lg][dd] = p;
    __syncthreads();
    if (tid < DD) f0[tid] = (f0p[0][tid] + f0p[1][tid] + f0p[2][tid] + f0p[3][tid]) * (1.0f / LL);
    __syncthreads();
    for (int o = tid; o < HH; o += 256) {
        float ah = iWh_b[o], ac = iWc_b[o];
        for (int d0 = 0; d0 < DD; d0 += 4) {
            const float4 wh = *(const float4*)(iWh_w + (size_t)o * DD + d0);
            const float4 wc = *(const float4*)(iWc_w + (size_t)o * DD + d0);
            ah += f0[d0] * wh.x + f0[d0 + 1] * wh.y + f0[d0 + 2] * wh.z + f0[d0 + 3] * wh.w;
            ac += f0[d0] * wc.x + f0[d0 + 1] * wc.y + f0[d0 + 2] * wc.z + f0[d0 + 3] * wc.w;
        }
        const float hv = tanhf(ah), cv = tanhf(ac);
        h[b * HH + o] = hv; c[b * HH + o] = cv;
        h16[b * HH + o] = (_Float16)hv;
    }
}

// ---------------- attention + visual (per step) ----------------
__global__ __launch_bounds__(256) void k_attn(int t,
        const float* __restrict__ feat, const _Float16* __restrict__ xp,
        const float* __restrict__ Wh, const float* __restrict__ v,
        const float* __restrict__ h, _Float16* __restrict__ V16) {
    __shared__ float sh[HH];
    __shared__ float hWhp[4][DD];
    __shared__ float hWh[DD];
    __shared__ float sv[DD];
    __shared__ float ep[LL][2];
    __shared__ float se[128];
    __shared__ float salpha[LL];
    __shared__ float red[128];
    const int b = blockIdx.x, tid = threadIdx.x;
    for (int e = tid; e < HH; e += 256) sh[e] = h[b * HH + e];
    if (tid < DD) sv[tid] = v[tid];
    __syncthreads();
    { const int a = tid & 63, q = tid >> 6;
      float p = 0;
      for (int k = q; k < HH; k += 4) p += sh[k] * Wh[k * DD + a];
      hWhp[q][a] = p; }
    __syncthreads();
    if (tid < DD) hWh[tid] = hWhp[0][tid] + hWhp[1][tid] + hWhp[2][tid] + hWhp[3][tid];
    __syncthreads();
    const size_t frow = (size_t)(b * TT + t) * RR;
    if (tid < 2 * LL) {
        const int l = tid >> 1, ah = (tid & 1) * 32;
        float acc = 0;
        const _Float16* xr = xp + frow + l * DD + ah;
        for (int a = 0; a < 32; ++a) acc += tanhf((float)xr[a] + hWh[ah + a]) * sv[ah + a];
        ep[l][tid & 1] = acc;
    }
    __syncthreads();
    if (tid < LL) se[tid] = ep[tid][0] + ep[tid][1];
    else if (tid < 128) se[tid] = -1e30f;
    __syncthreads();
    if (tid < 128) red[tid] = se[tid];
    __syncthreads();
    for (int s = 64; s; s >>= 1) { if (tid < s) red[tid] = fmaxf(red[tid], red[tid + s]); __syncthreads(); }
    const float mx = red[0];
    __syncthreads();
    float ex = 0.f;
    if (tid < LL) { ex = expf(se[tid] - mx); salpha[tid] = ex; }
    if (tid < 128) red[tid] = ex;
    __syncthreads();
    for (int s = 64; s; s >>= 1) { if (tid < s) red[tid] += red[tid + s]; __syncthreads(); }
    const float inv = 1.f / red[0];
    __syncthreads();
    if (tid < LL) salpha[tid] *= inv;
    __syncthreads();
    _Float16* vout = V16 + ((size_t)t * NB + b) * RR;
    const float* fr = feat + frow;
    for (int e = tid; e < RR; e += 256) vout[e] = (_Float16)(fr[e] * salpha[e >> 6]);
}

// ---------------- shared MFMA K-segment ----------------
__device__ __forceinline__ void mfma_seg(const _Float16* __restrict__ Ap,
        const _Float16* __restrict__ A2, const _Float16* __restrict__ Bp,
        const _Float16* __restrict__ B2, int k0, int kend,
        floatx16& acc00, floatx16& acc01, floatx16& acc10, floatx16& acc11) {
    for (; k0 < kend; k0 += 16) {
        const half8 a0 = *(const half8*)(Ap + k0);
        const half8 a1 = *(const half8*)(A2 + k0);
        const half8 b0 = *(const half8*)(Bp + k0);
        const half8 b1 = *(const half8*)(B2 + k0);
        acc00 = __builtin_amdgcn_mfma_f32_32x32x16_f16(a0, b0, acc00, 0, 0, 0);
        acc01 = __builtin_amdgcn_mfma_f32_32x32x16_f16(a0, b1, acc01, 0, 0, 0);
        acc10 = __builtin_amdgcn_mfma_f32_32x32x16_f16(a1, b0, acc10, 0, 0, 0);
        acc11 = __builtin_amdgcn_mfma_f32_32x32x16_f16(a1, b1, acc11, 0, 0, 0);
    }
}

// ---------------- gates GEMM (per step), split-K=8 ----------------
__global__ __launch_bounds__(256) void k_gates(int t, const _Float16* __restrict__ V16,
        const _Float16* __restrict__ h16, const _Float16* __restrict__ Wih,
        const _Float16* __restrict__ Whh, float* __restrict__ gpart) {
    const int ns = blockIdx.x >> 3, sp = blockIdx.x & 7;
    const int tid = threadIdx.x, w = tid >> 6, ln = tid & 63;
    const int lr = ln & 31, kg = (ln >> 5) * 8;
    const int n0 = ns * 256 + w * 64;
    const int kbeg = sp * 848, kend = kbeg + 848;     // 8*848 = 6784
    floatx16 acc00, acc01, acc10, acc11;
    for (int i = 0; i < 16; ++i) { acc00[i] = 0.f; acc01[i] = 0.f; acc10[i] = 0.f; acc11[i] = 0.f; }
    const _Float16* Vt = V16 + (size_t)t * NB * RR;
    { const int ke = kend < RR ? kend : RR;
      if (kbeg < ke)
          mfma_seg(Vt + (size_t)lr * RR + kg, Vt + (size_t)(lr + 32) * RR + kg,
                   Wih + (size_t)(n0 + lr) * RR + kg, Wih + (size_t)(n0 + 32 + lr) * RR + kg,
                   kbeg, ke, acc00, acc01, acc10, acc11); }
    { const int ks = kbeg > RR ? kbeg : RR;
      if (ks < kend)
          mfma_seg(h16 + (size_t)lr * HH + kg, h16 + (size_t)(lr + 32) * HH + kg,
                   Whh + (size_t)(n0 + lr) * HH + kg, Whh + (size_t)(n0 + 32 + lr) * HH + kg,
                   ks - RR, kend - RR, acc00, acc01, acc10, acc11); }
    float* P = gpart + (size_t)sp * (NB * NG);
    const int rbase = 4 * (ln >> 5);
#pragma unroll
    for (int r = 0; r < 16; ++r) {
        const int row = rbase + (r & 3) + 8 * (r >> 2);
        P[(size_t)row * NG + n0 + lr]           = acc00[r];
        P[(size_t)row * NG + n0 + 32 + lr]      = acc01[r];
        P[(size_t)(row + 32) * NG + n0 + lr]    = acc10[r];
        P[(size_t)(row + 32) * NG + n0 + 32 + lr] = acc11[r];
    }
}

// ---------------- LSTM cell (per step): reduce split-K + pointwise ----------------
__global__ __launch_bounds__(256) void k_cell(int t, const float* __restrict__ gpart,
        const float* __restrict__ b_ih, const float* __restrict__ b_hh,
        float* __restrict__ h, float* __restrict__ c, _Float16* __restrict__ h16,
        _Float16* __restrict__ H16) {
    const int idx = blockIdx.x * 256 + threadIdx.x;   // 0..65535
    const int b = idx >> 10, j = idx & 1023;
    float gi = 0, gf = 0, gg = 0, go = 0;
    for (int sp = 0; sp < 8; ++sp) {
        const float* P = gpart + (size_t)sp * (NB * NG) + (size_t)b * NG;
        gi += P[j]; gf += P[HH + j]; gg += P[2 * HH + j]; go += P[3 * HH + j];
    }
    gi += b_ih[j] + b_hh[j];
    gf += b_ih[HH + j] + b_hh[HH + j];
    gg += b_ih[2 * HH + j] + b_hh[2 * HH + j];
    go += b_ih[3 * HH + j] + b_hh[3 * HH + j];
    const float cv = sigm(gf) * c[idx] + sigm(gi) * tanhf(gg);
    const float hv = sigm(go) * tanhf(cv);
    c[idx] = cv; h[idx] = hv;
    h16[idx] = (_Float16)hv;
    H16[(size_t)t * NB * HH + idx] = (_Float16)hv;
}

// ---------------- deferred head GEMM: M = H@Wh^T + V@Wy^T (split-K=4) ----------------
__global__ __launch_bounds__(512) void k_head(const _Float16* __restrict__ V16,
        const _Float16* __restrict__ H16, const _Float16* __restrict__ Wy,
        const _Float16* __restrict__ Whw, float* __restrict__ Mpart) {
    const int bid = blockIdx.x;                    // 160 blocks: rt(10) x ns(4) x sp(4)
    const int sp = bid & 3, ns = (bid >> 2) & 3, rt = bid >> 4;
    const int tid = threadIdx.x, w = tid >> 6, ln = tid & 63;
    const int lr = ln & 31, kg = (ln >> 5) * 8;
    const int m0 = rt * 128 + (w >> 2) * 64;
    const int n0 = ns * 256 + (w & 3) * 64;
    const int kbeg = sp * 1696, kend = kbeg + 1696;   // 4*1696 = 6784
    floatx16 acc00, acc01, acc10, acc11;
    for (int i = 0; i < 16; ++i) { acc00[i] = 0.f; acc01[i] = 0.f; acc10[i] = 0.f; acc11[i] = 0.f; }
    { const int ke = kend < RR ? kend : RR;
      if (kbeg < ke)
          mfma_seg(V16 + (size_t)(m0 + lr) * RR + kg, V16 + (size_t)(m0 + 32 + lr) * RR + kg,
                   Wy + (size_t)(n0 + lr) * RR + kg, Wy + (size_t)(n0 + 32 + lr) * RR + kg,
                   kbeg, ke, acc00, acc01, acc10, acc11); }
    { const int ks = kbeg > RR ? kbeg : RR;
      if (ks < kend)
          mfma_seg(H16 + (size_t)(m0 + lr) * HH + kg, H16 + (size_t)(m0 + 32 + lr) * HH + kg,
                   Whw + (size_t)(n0 + lr) * HH + kg, Whw + (size_t)(n0 + 32 + lr) * HH + kg,
                   ks - RR, kend - RR, acc00, acc01, acc10, acc11); }
    float* P = Mpart + (size_t)sp * (1280 * MM);
    const int rbase = 4 * (ln >> 5);
#pragma unroll
    for (int r = 0; r < 16; ++r) {
        const int row = m0 + rbase + (r & 3) + 8 * (r >> 2);
        P[(size_t)row * MM + n0 + lr]             = acc00[r];
        P[(size_t)row * MM + n0 + 32 + lr]        = acc01[r];
        P[(size_t)(row + 32) * MM + n0 + lr]      = acc10[r];
        P[(size_t)(row + 32) * MM + n0 + 32 + lr] = acc11[r];
    }
}

// ---------------- final: out = (M + Wh_b) @ Wu^T + Wu_b ----------------
__global__ __launch_bounds__(256) void k_final(const float* __restrict__ Mpart,
        const float* __restrict__ Whb, const float* __restrict__ Wu,
        const float* __restrict__ Wub, float* __restrict__ out) {
    __shared__ float sm[MM];
    __shared__ float rd[12];
    const int r = blockIdx.x, tid = threadIdx.x;     // r = t*64 + b
    for (int e = tid; e < MM; e += 256) {
        float x = Whb[e];
        for (int sp = 0; sp < 4; ++sp) x += Mpart[((size_t)sp * 1280 + r) * MM + e];
        sm[e] = x;
    }
    __syncthreads();
    float p0 = 0, p1 = 0, p2 = 0;
    for (int e = tid; e < MM; e += 256) {
        const float mv = sm[e];
        p0 += mv * Wu[e]; p1 += mv * Wu[MM + e]; p2 += mv * Wu[2 * MM + e];
    }
    float q[3] = {p0, p1, p2};
    for (int j = 0; j < 3; ++j) {
        float x = q[j];
        for (int o = 32; o > 0; o >>= 1) x += __shfl_down(x, o, 64);
        if ((tid & 63) == 0) rd[(tid >> 6) * 3 + j] = x;
    }
    __syncthreads();
    if (tid < 3) {
        const float x = rd[tid] + rd[3 + tid] + rd[6 + tid] + rd[9 + tid] + Wub[tid];
        const int b = r & 63, ts = r >> 6;
        out[((size_t)b * TT + ts) * 3 + tid] = x;
    }
}

extern "C" void kernel_launch(void* const* d_in, const int* in_sizes, int n_in,
                              void* d_out, int out_size, void* d_ws, size_t ws_size,
                              hipStream_t stream) {
    (void)in_sizes; (void)n_in; (void)out_size;
    const float* feature = (const float*)d_in[0];
    const float* attn_Wx = (const float*)d_in[1];
    const float* attn_Wh = (const float*)d_in[2];
    const float* attn_v  = (const float*)d_in[3];
    const float* W_ih    = (const float*)d_in[4];
    const float* W_hh    = (const float*)d_in[5];
    const float* b_ih    = (const float*)d_in[6];
    const float* b_hh    = (const float*)d_in[7];
    const float* Wh_w    = (const float*)d_in[8];
    const float* Wh_b    = (const float*)d_in[9];
    const float* Wy_w    = (const float*)d_in[10];
    const float* Wu_w    = (const float*)d_in[11];
    const float* Wu_b    = (const float*)d_in[12];
    const float* iWh_w   = (const float*)d_in[13];
    const float* iWh_b   = (const float*)d_in[14];
    const float* iWc_w   = (const float*)d_in[15];
    const float* iWc_b   = (const float*)d_in[16];
    float* out = (float*)d_out;

    char* ws = (char*)d_ws;
    size_t off = 0;
    auto alloc = [&](size_t bytes) { void* p = ws + off; off += (bytes + 255) & ~(size_t)255; return p; };
    _Float16* Wih16 = (_Float16*)alloc((size_t)NG * RR * 2);
    _Float16* Whh16 = (_Float16*)alloc((size_t)NG * HH * 2);
    _Float16* Wy16  = (_Float16*)alloc((size_t)MM * RR * 2);
    _Float16* Whw16 = (_Float16*)alloc((size_t)MM * HH * 2);
    _Float16* xp16  = (_Float16*)alloc((size_t)1280 * RR * 2);
    _Float16* V16   = (_Float16*)alloc((size_t)TT * NB * RR * 2);
    _Float16* H16   = (_Float16*)alloc((size_t)TT * NB * HH * 2);
    float*    hbuf  = (float*)alloc((size_t)NB * HH * 4);
    float*    cbuf  = (float*)alloc((size_t)NB * HH * 4);
    _Float16* h16   = (_Float16*)alloc((size_t)NB * HH * 2);
    float*    gpart = (float*)alloc((size_t)8 * NB * NG * 4);
    float*    Mpart = (float*)alloc((size_t)4 * 1280 * MM * 4);
    if (ws_size < off) return;   // refuse to scribble out of bounds

    // one-time weight conversions + xproj + init
    k_conv<<<(NG * RR / 4 + 255) / 256, 256, 0, stream>>>(W_ih, Wih16, NG * RR);
    k_conv<<<(NG * HH / 4 + 255) / 256, 256, 0, stream>>>(W_hh, Whh16, NG * HH);
    k_conv<<<(MM * RR / 4 + 255) / 256, 256, 0, stream>>>(Wy_w, Wy16, MM * RR);
    k_conv<<<(MM * HH / 4 + 255) / 256, 256, 0, stream>>>(Wh_w, Whw16, MM * HH);
    k_xproj<<<1280, 256, 0, stream>>>(feature, attn_Wx, xp16);
    k_init<<<64, 256, 0, stream>>>(feature, iWh_w, iWh_b, iWc_w, iWc_b, hbuf, cbuf, h16);

    for (int t = 0; t < TT; ++t) {
        k_attn<<<64, 256, 0, stream>>>(t, feature, xp16, attn_Wh, attn_v, hbuf, V16);
        k_gates<<<128, 256, 0, stream>>>(t, V16, h16, Wih16, Whh16, gpart);
        k_cell<<<256, 256, 0, stream>>>(t, gpart, b_ih, b_hh, hbuf, cbuf, h16, H16);
    }

    k_head<<<160, 512, 0, stream>>>(V16, H16, Wy16, Whw16, Mpart);
    k_final<<<1280, 256, 0, stream>>>(Mpart, Wh_b, Wu_w, Wu_b, out);
}

// Round 2
// 1856.485 us; speedup vs baseline: 1.2268x; 1.2268x over previous
//
#include <hip/hip_runtime.h>
#include <math.h>

typedef _Float16 half8 __attribute__((ext_vector_type(8)));
typedef _Float16 half4v __attribute__((ext_vector_type(4)));
typedef float floatx16 __attribute__((ext_vector_type(16)));

#define TT 20
#define NB 64      // batch per step
#define LL 90
#define DD 64
#define RR 5760    // L*D
#define HH 1024
#define NG 4096    // 4*H
#define MM 1024
#define CH0 90     // chunks in K-part0 (5760/64)
#define CHT 106    // total 64-half chunks (6784/64)

__device__ __forceinline__ float sigm(float x) { return 1.f / (1.f + expf(-x)); }

// ---------------- fp32 -> fp16 convert ----------------
__global__ __launch_bounds__(256) void k_conv(const float* __restrict__ s,
                                              _Float16* __restrict__ d, int n) {
    int i = (blockIdx.x * 256 + threadIdx.x) * 4;
    if (i + 4 <= n) {
        const float4 v = *(const float4*)(s + i);
        half4v o;
        o[0] = (_Float16)v.x; o[1] = (_Float16)v.y;
        o[2] = (_Float16)v.z; o[3] = (_Float16)v.w;
        *(half4v*)(d + i) = o;
    } else {
        for (; i < n; ++i) d[i] = (_Float16)s[i];
    }
}

// ---------------- xproj = feature @ attn_Wx  -> fp16 [1280][90][64] ----------------
__global__ __launch_bounds__(256) void k_xproj(const float* __restrict__ feat,
                                               const float* __restrict__ Wx,
                                               _Float16* __restrict__ xp) {
    __shared__ float sWx[DD * DD];
    __shared__ float sx[16 * DD];
    const int row = blockIdx.x;            // 0..1279  (= b*TT + t)
    const int tid = threadIdx.x;
    for (int e = tid * 4; e < DD * DD; e += 1024)
        *(float4*)(sWx + e) = *(const float4*)(Wx + e);
    const int a4 = tid & 15, lg = tid >> 4;
    const float* frow = feat + (size_t)row * RR;
    for (int lb = 0; lb < LL; lb += 16) {
        __syncthreads();
        { int e = tid * 4; int ls = e >> 6, dd = e & 63;
          if (lb + ls < LL) *(float4*)(sx + e) = *(const float4*)(frow + (lb + ls) * DD + dd); }
        __syncthreads();
        const int l = lb + lg;
        if (l < LL) {
            float a0 = 0, a1 = 0, a2 = 0, a3 = 0;
            for (int dd = 0; dd < DD; ++dd) {
                const float xv = sx[lg * DD + dd];
                const float4 wv = *(const float4*)(sWx + dd * DD + a4 * 4);
                a0 += xv * wv.x; a1 += xv * wv.y; a2 += xv * wv.z; a3 += xv * wv.w;
            }
            half4v o;
            o[0] = (_Float16)a0; o[1] = (_Float16)a1; o[2] = (_Float16)a2; o[3] = (_Float16)a3;
            *(half4v*)(xp + (size_t)row * RR + l * DD + a4 * 4) = o;
        }
    }
}

// ---------------- init h0, c0 ----------------
__global__ __launch_bounds__(256) void k_init(const float* __restrict__ feat,
        const float* __restrict__ iWh_w, const float* __restrict__ iWh_b,
        const float* __restrict__ iWc_w, const float* __restrict__ iWc_b,
        float* __restrict__ h, float* __restrict__ c, _Float16* __restrict__ h16) {
    __shared__ float f0p[4][DD];
    __shared__ float f0[DD];
    const int b = blockIdx.x, tid = threadIdx.x;
    const int dd = tid & 63, lg = tid >> 6;
    const float* frow = feat + (size_t)(b * TT) * RR;   // t = 0
    float p = 0;
    for (int l = lg; l < LL; l += 4) p += frow[l * DD + dd];
    f0p[lg][dd] = p;
    __syncthreads();
    if (tid < DD) f0[tid] = (f0p[0][tid] + f0p[1][tid] + f0p[2][tid] + f0p[3][tid]) * (1.0f / LL);
    __syncthreads();
    for (int o = tid; o < HH; o += 256) {
        float ah = iWh_b[o], ac = iWc_b[o];
        for (int d0 = 0; d0 < DD; d0 += 4) {
            const float4 wh = *(const float4*)(iWh_w + (size_t)o * DD + d0);
            const float4 wc = *(const float4*)(iWc_w + (size_t)o * DD + d0);
            ah += f0[d0] * wh.x + f0[d0 + 1] * wh.y + f0[d0 + 2] * wh.z + f0[d0 + 3] * wh.w;
            ac += f0[d0] * wc.x + f0[d0 + 1] * wc.y + f0[d0 + 2] * wc.z + f0[d0 + 3] * wc.w;
        }
        const float hv = tanhf(ah), cv = tanhf(ac);
        h[b * HH + o] = hv; c[b * HH + o] = cv;
        h16[b * HH + o] = (_Float16)hv;
    }
}

// ---------------- attention + visual (t = 0 only) ----------------
__global__ __launch_bounds__(256) void k_attn(int t,
        const float* __restrict__ feat, const _Float16* __restrict__ xp,
        const float* __restrict__ Wh, const float* __restrict__ v,
        const float* __restrict__ h, _Float16* __restrict__ V16) {
    __shared__ float sh[HH];
    __shared__ float hWhp[4][DD];
    __shared__ float hWh[DD];
    __shared__ float sv[DD];
    __shared__ float ep[LL][2];
    __shared__ float se[128];
    __shared__ float salpha[LL];
    __shared__ float red[128];
    const int b = blockIdx.x, tid = threadIdx.x;
    for (int e = tid; e < HH; e += 256) sh[e] = h[b * HH + e];
    if (tid < DD) sv[tid] = v[tid];
    __syncthreads();
    { const int a = tid & 63, q = tid >> 6;
      float p = 0;
      for (int k = q; k < HH; k += 4) p += sh[k] * Wh[k * DD + a];
      hWhp[q][a] = p; }
    __syncthreads();
    if (tid < DD) hWh[tid] = hWhp[0][tid] + hWhp[1][tid] + hWhp[2][tid] + hWhp[3][tid];
    __syncthreads();
    const size_t frow = (size_t)(b * TT + t) * RR;
    if (tid < 2 * LL) {
        const int l = tid >> 1, ah = (tid & 1) * 32;
        float acc = 0;
        const _Float16* xr = xp + frow + l * DD + ah;
        for (int a = 0; a < 32; ++a) acc += tanhf((float)xr[a] + hWh[ah + a]) * sv[ah + a];
        ep[l][tid & 1] = acc;
    }
    __syncthreads();
    if (tid < LL) se[tid] = ep[tid][0] + ep[tid][1];
    else if (tid < 128) se[tid] = -1e30f;
    __syncthreads();
    if (tid < 128) red[tid] = se[tid];
    __syncthreads();
    for (int s = 64; s; s >>= 1) { if (tid < s) red[tid] = fmaxf(red[tid], red[tid + s]); __syncthreads(); }
    const float mx = red[0];
    __syncthreads();
    float ex = 0.f;
    if (tid < LL) { ex = expf(se[tid] - mx); salpha[tid] = ex; }
    if (tid < 128) red[tid] = ex;
    __syncthreads();
    for (int s = 64; s; s >>= 1) { if (tid < s) red[tid] += red[tid + s]; __syncthreads(); }
    const float inv = 1.f / red[0];
    __syncthreads();
    if (tid < LL) salpha[tid] *= inv;
    __syncthreads();
    _Float16* vout = V16 + ((size_t)t * NB + b) * RR;
    const float* fr = feat + frow;
    for (int e = tid; e < RR; e += 256) vout[e] = (_Float16)(fr[e] * salpha[e >> 6]);
}

// ================= tiled GEMM machinery =================
// stage a 64-row x 128-byte tile (8 KB) into LDS, XOR-16 swizzled source.
__device__ __forceinline__ void stage_tile(const char* src, size_t stride, char* lds, int ln) {
    const char* g = src + (size_t)(ln >> 3) * stride + (((ln & 7) ^ (ln >> 3)) << 4);
#pragma unroll
    for (int i = 0; i < 8; ++i)
        __builtin_amdgcn_global_load_lds(
            (const __attribute__((address_space(1))) void*)(g + (size_t)(i * 8) * stride),
            (__attribute__((address_space(3))) void*)(lds + i * 1024), 16, 0, 0);
}

struct Src2 { const char* p0; size_t s0; const char* p1; size_t s1; };

__device__ __forceinline__ const char* chunk_ptr(const Src2& s, int c, size_t& stride) {
    if (c < CH0) { stride = s.s0; return s.p0 + (size_t)c * 128; }
    stride = s.s1; return s.p1 + (size_t)(c - CH0) * 128;
}

// C[M,N] = [A0|A1] @ [B0|B1]^T.  Rows of A0/B0 are RR halves, A1/B1 are HH halves.
// grid = mt * NT * SB blocks; block = 2 waves; each wave: 64x64 output over
// K-chunks start..CHT step SB*2; in-block 2-way K reduce via LDS; kb -> partial.
template<int NT, int SB>
__global__ __launch_bounds__(128) void k_gemm(
        const _Float16* __restrict__ A0, const _Float16* __restrict__ A1,
        const _Float16* __restrict__ B0, const _Float16* __restrict__ B1,
        float* __restrict__ C, int ldc, size_t part_elems) {
    __shared__ char smem[65536];
    const int bid = blockIdx.x;
    const int kb = bid % SB;
    const int nt = (bid / SB) % NT;
    const int mt = bid / (SB * NT);
    const int tid = threadIdx.x, w = tid >> 6, ln = tid & 63;
    char* wlds = smem + w * 32768;

    const int arow = mt * 64, brow = nt * 64;
    Src2 As = { (const char*)(A0 + (size_t)arow * RR), (size_t)RR * 2,
                (const char*)(A1 + (size_t)arow * HH), (size_t)HH * 2 };
    Src2 Bs = { (const char*)(B0 + (size_t)brow * RR), (size_t)RR * 2,
                (const char*)(B1 + (size_t)brow * HH), (size_t)HH * 2 };

    floatx16 acc00, acc01, acc10, acc11;
#pragma unroll
    for (int i = 0; i < 16; ++i) { acc00[i] = 0.f; acc01[i] = 0.f; acc10[i] = 0.f; acc11[i] = 0.f; }

    const int start = kb * 2 + w;
    const int STRIDE = SB * 2;
    const int r = ln & 31;
    const int xsw = (r & 7) << 4;
    const int fo = (ln >> 5) * 16;
    const int rbyte = r * 128;

    int c = c = start, bsel = 0;
    { size_t st; const char* p = chunk_ptr(As, c, st); stage_tile(p, st, wlds, ln);
      p = chunk_ptr(Bs, c, st); stage_tile(p, st, wlds + 8192, ln); }
    while (true) {
        const int cn = c + STRIDE;
        if (cn < CHT) {
            char* nl = wlds + ((bsel ^ 1) << 14);
            size_t st; const char* p = chunk_ptr(As, cn, st); stage_tile(p, st, nl, ln);
            p = chunk_ptr(Bs, cn, st); stage_tile(p, st, nl + 8192, ln);
            asm volatile("s_waitcnt vmcnt(16)" ::: "memory");
        } else {
            asm volatile("s_waitcnt vmcnt(0)" ::: "memory");
        }
        __builtin_amdgcn_sched_barrier(0);
        const char* LA = wlds + (bsel << 14);
        const char* LB = LA + 8192;
#pragma unroll
        for (int kk = 0; kk < 4; ++kk) {
            const int o = ((kk * 32 + fo) ^ xsw);
            const half8 a0 = *(const half8*)(LA + rbyte + o);
            const half8 a1 = *(const half8*)(LA + 4096 + rbyte + o);
            const half8 b0 = *(const half8*)(LB + rbyte + o);
            const half8 b1 = *(const half8*)(LB + 4096 + rbyte + o);
            acc00 = __builtin_amdgcn_mfma_f32_32x32x16_f16(a0, b0, acc00, 0, 0, 0);
            acc01 = __builtin_amdgcn_mfma_f32_32x32x16_f16(a0, b1, acc01, 0, 0, 0);
            acc10 = __builtin_amdgcn_mfma_f32_32x32x16_f16(a1, b0, acc10, 0, 0, 0);
            acc11 = __builtin_amdgcn_mfma_f32_32x32x16_f16(a1, b1, acc11, 0, 0, 0);
        }
        if (cn >= CHT) break;
        c = cn; bsel ^= 1;
    }
    __syncthreads();
    // dump accs into per-wave reduce region (reuse staging LDS)
    float* Rg = (float*)(smem + w * 16384);
    const int rbase = 4 * (ln >> 5), lr = ln & 31;
#pragma unroll
    for (int q = 0; q < 16; ++q) {
        const int row = rbase + (q & 3) + 8 * (q >> 2);
        Rg[row * 64 + lr]             = acc00[q];
        Rg[row * 64 + 32 + lr]        = acc01[q];
        Rg[(row + 32) * 64 + lr]      = acc10[q];
        Rg[(row + 32) * 64 + 32 + lr] = acc11[q];
    }
    __syncthreads();
    const float* R0 = (const float*)smem;
    const float* R1 = (const float*)(smem + 16384);
    float* Cout = C + (size_t)kb * part_elems;
    for (int e = tid * 4; e < 4096; e += 512) {
        const float4 u = *(const float4*)(R0 + e);
        const float4 v2 = *(const float4*)(R1 + e);
        float4 s2; s2.x = u.x + v2.x; s2.y = u.y + v2.y; s2.z = u.z + v2.z; s2.w = u.w + v2.w;
        const int row = e >> 6, col = e & 63;
        *(float4*)(Cout + (size_t)(arow + row) * ldc + brow + col) = s2;
    }
}

// ---------------- fused LSTM cell (step t) + attention (step t+1) ----------------
__global__ __launch_bounds__(256) void k_cellattn(int t,
        const float* __restrict__ gpart, const float* __restrict__ b_ih,
        const float* __restrict__ b_hh, float* __restrict__ cbuf,
        _Float16* __restrict__ h16, _Float16* __restrict__ H16,
        const float* __restrict__ feat, const _Float16* __restrict__ xp,
        const float* __restrict__ Wh, const float* __restrict__ v,
        _Float16* __restrict__ V16) {
    __shared__ float sh[HH];
    __shared__ float hWhp[4][DD];
    __shared__ float hWh[DD];
    __shared__ float sv[DD];
    __shared__ float ep[LL][2];
    __shared__ float se[128];
    __shared__ float salpha[LL];
    __shared__ float red[128];
    const int b = blockIdx.x, tid = threadIdx.x;
    if (tid < DD) sv[tid] = v[tid];
    // ----- cell: 4 hidden units per thread -----
    const int j0 = tid * 4;
    float ag[4][4];
#pragma unroll
    for (int g4 = 0; g4 < 4; ++g4)
        for (int q = 0; q < 4; ++q) ag[g4][q] = 0.f;
    for (int sp = 0; sp < 4; ++sp) {
        const float* P = gpart + ((size_t)sp * NB + b) * NG;
#pragma unroll
        for (int g4 = 0; g4 < 4; ++g4) {
            const float4 pv = *(const float4*)(P + g4 * HH + j0);
            ag[g4][0] += pv.x; ag[g4][1] += pv.y; ag[g4][2] += pv.z; ag[g4][3] += pv.w;
        }
    }
#pragma unroll
    for (int g4 = 0; g4 < 4; ++g4) {
        const float4 bi = *(const float4*)(b_ih + g4 * HH + j0);
        const float4 bh = *(const float4*)(b_hh + g4 * HH + j0);
        ag[g4][0] += bi.x + bh.x; ag[g4][1] += bi.y + bh.y;
        ag[g4][2] += bi.z + bh.z; ag[g4][3] += bi.w + bh.w;
    }
    float4 cold = *(const float4*)(cbuf + (size_t)b * HH + j0);
    float co[4] = { cold.x, cold.y, cold.z, cold.w };
    float4 cnew; half4v hh4;
    float hv4[4];
#pragma unroll
    for (int q = 0; q < 4; ++q) {
        const float cv = sigm(ag[1][q]) * co[q] + sigm(ag[0][q]) * tanhf(ag[2][q]);
        const float hv = sigm(ag[3][q]) * tanhf(cv);
        hv4[q] = hv;
        ((float*)&cnew)[q] = cv;
        hh4[q] = (_Float16)hv;
        sh[j0 + q] = hv;
    }
    *(float4*)(cbuf + (size_t)b * HH + j0) = cnew;
    *(half4v*)(h16 + (size_t)b * HH + j0) = hh4;
    *(half4v*)(H16 + ((size_t)t * NB + b) * HH + j0) = hh4;
    __syncthreads();
    if (t + 1 >= TT) return;
    // ----- attention for step t+1 using sh -----
    { const int a = tid & 63, q = tid >> 6;
      float p = 0;
      for (int k = q; k < HH; k += 4) p += sh[k] * Wh[k * DD + a];
      hWhp[q][a] = p; }
    __syncthreads();
    if (tid < DD) hWh[tid] = hWhp[0][tid] + hWhp[1][tid] + hWhp[2][tid] + hWhp[3][tid];
    __syncthreads();
    const size_t frow = (size_t)(b * TT + t + 1) * RR;
    if (tid < 2 * LL) {
        const int l = tid >> 1, ah = (tid & 1) * 32;
        float acc = 0;
        const _Float16* xr = xp + frow + l * DD + ah;
        for (int a = 0; a < 32; ++a) acc += tanhf((float)xr[a] + hWh[ah + a]) * sv[ah + a];
        ep[l][tid & 1] = acc;
    }
    __syncthreads();
    if (tid < LL) se[tid] = ep[tid][0] + ep[tid][1];
    else if (tid < 128) se[tid] = -1e30f;
    __syncthreads();
    if (tid < 128) red[tid] = se[tid];
    __syncthreads();
    for (int s = 64; s; s >>= 1) { if (tid < s) red[tid] = fmaxf(red[tid], red[tid + s]); __syncthreads(); }
    const float mx = red[0];
    __syncthreads();
    float ex = 0.f;
    if (tid < LL) { ex = expf(se[tid] - mx); salpha[tid] = ex; }
    if (tid < 128) red[tid] = ex;
    __syncthreads();
    for (int s = 64; s; s >>= 1) { if (tid < s) red[tid] += red[tid + s]; __syncthreads(); }
    const float inv = 1.f / red[0];
    __syncthreads();
    if (tid < LL) salpha[tid] *= inv;
    __syncthreads();
    _Float16* vout = V16 + ((size_t)(t + 1) * NB + b) * RR;
    const float* fr = feat + frow;
    for (int e = tid; e < RR; e += 256) vout[e] = (_Float16)(fr[e] * salpha[e >> 6]);
}

// ---------------- final: out = (M + Wh_b) @ Wu^T + Wu_b ----------------
__global__ __launch_bounds__(256) void k_final(const float* __restrict__ Mbuf,
        const float* __restrict__ Whb, const float* __restrict__ Wu,
        const float* __restrict__ Wub, float* __restrict__ out) {
    __shared__ float sm[MM];
    __shared__ float rd[12];
    const int r = blockIdx.x, tid = threadIdx.x;     // r = t*64 + b
    for (int e = tid; e < MM; e += 256)
        sm[e] = Whb[e] + Mbuf[(size_t)r * MM + e];
    __syncthreads();
    float p0 = 0, p1 = 0, p2 = 0;
    for (int e = tid; e < MM; e += 256) {
        const float mv = sm[e];
        p0 += mv * Wu[e]; p1 += mv * Wu[MM + e]; p2 += mv * Wu[2 * MM + e];
    }
    float q[3] = {p0, p1, p2};
    for (int j = 0; j < 3; ++j) {
        float x = q[j];
        for (int o = 32; o > 0; o >>= 1) x += __shfl_down(x, o, 64);
        if ((tid & 63) == 0) rd[(tid >> 6) * 3 + j] = x;
    }
    __syncthreads();
    if (tid < 3) {
        const float x = rd[tid] + rd[3 + tid] + rd[6 + tid] + rd[9 + tid] + Wub[tid];
        const int b = r & 63, ts = r >> 6;
        out[((size_t)b * TT + ts) * 3 + tid] = x;
    }
}

extern "C" void kernel_launch(void* const* d_in, const int* in_sizes, int n_in,
                              void* d_out, int out_size, void* d_ws, size_t ws_size,
                              hipStream_t stream) {
    (void)in_sizes; (void)n_in; (void)out_size;
    const float* feature = (const float*)d_in[0];
    const float* attn_Wx = (const float*)d_in[1];
    const float* attn_Wh = (const float*)d_in[2];
    const float* attn_v  = (const float*)d_in[3];
    const float* W_ih    = (const float*)d_in[4];
    const float* W_hh    = (const float*)d_in[5];
    const float* b_ih    = (const float*)d_in[6];
    const float* b_hh    = (const float*)d_in[7];
    const float* Wh_w    = (const float*)d_in[8];
    const float* Wh_b    = (const float*)d_in[9];
    const float* Wy_w    = (const float*)d_in[10];
    const float* Wu_w    = (const float*)d_in[11];
    const float* Wu_b    = (const float*)d_in[12];
    const float* iWh_w   = (const float*)d_in[13];
    const float* iWh_b   = (const float*)d_in[14];
    const float* iWc_w   = (const float*)d_in[15];
    const float* iWc_b   = (const float*)d_in[16];
    float* out = (float*)d_out;

    char* ws = (char*)d_ws;
    size_t off = 0;
    auto alloc = [&](size_t bytes) { void* p = ws + off; off += (bytes + 255) & ~(size_t)255; return p; };
    _Float16* Wih16 = (_Float16*)alloc((size_t)NG * RR * 2);
    _Float16* Whh16 = (_Float16*)alloc((size_t)NG * HH * 2);
    _Float16* Wy16  = (_Float16*)alloc((size_t)MM * RR * 2);
    _Float16* Whw16 = (_Float16*)alloc((size_t)MM * HH * 2);
    _Float16* xp16  = (_Float16*)alloc((size_t)1280 * RR * 2);
    _Float16* V16   = (_Float16*)alloc((size_t)TT * NB * RR * 2);
    _Float16* H16   = (_Float16*)alloc((size_t)TT * NB * HH * 2);
    float*    hbuf  = (float*)alloc((size_t)NB * HH * 4);
    float*    cbuf  = (float*)alloc((size_t)NB * HH * 4);
    _Float16* h16   = (_Float16*)alloc((size_t)NB * HH * 2);
    float*    gpart = (float*)alloc((size_t)4 * NB * NG * 4);
    float*    Mbuf  = (float*)alloc((size_t)1280 * MM * 4);
    if (ws_size < off) return;   // refuse to scribble out of bounds

    // one-time weight conversions + xproj + init + attn(0)
    k_conv<<<(NG * RR / 4 + 255) / 256, 256, 0, stream>>>(W_ih, Wih16, NG * RR);
    k_conv<<<(NG * HH / 4 + 255) / 256, 256, 0, stream>>>(W_hh, Whh16, NG * HH);
    k_conv<<<(MM * RR / 4 + 255) / 256, 256, 0, stream>>>(Wy_w, Wy16, MM * RR);
    k_conv<<<(MM * HH / 4 + 255) / 256, 256, 0, stream>>>(Wh_w, Whw16, MM * HH);
    k_xproj<<<1280, 256, 0, stream>>>(feature, attn_Wx, xp16);
    k_init<<<64, 256, 0, stream>>>(feature, iWh_w, iWh_b, iWc_w, iWc_b, hbuf, cbuf, h16);
    k_attn<<<64, 256, 0, stream>>>(0, feature, xp16, attn_Wh, attn_v, hbuf, V16);

    for (int t = 0; t < TT; ++t) {
        const _Float16* Vt = V16 + (size_t)t * NB * RR;
        k_gemm<64, 4><<<256, 128, 0, stream>>>(Vt, h16, Wih16, Whh16,
                                               gpart, NG, (size_t)NB * NG);
        k_cellattn<<<64, 256, 0, stream>>>(t, gpart, b_ih, b_hh, cbuf, h16, H16,
                                           feature, xp16, attn_Wh, attn_v, V16);
    }

    k_gemm<16, 1><<<320, 128, 0, stream>>>(V16, H16, Wy16, Whw16, Mbuf, MM, 0);
    k_final<<<1280, 256, 0, stream>>>(Mbuf, Wh_b, Wu_w, Wu_b, out);
}

// Round 3
// 603.394 us; speedup vs baseline: 3.7745x; 3.0767x over previous
//
#include <hip/hip_runtime.h>
#include <math.h>

typedef _Float16 half8 __attribute__((ext_vector_type(8)));
typedef _Float16 half4v __attribute__((ext_vector_type(4)));
typedef _Float16 half2v __attribute__((ext_vector_type(2)));
typedef float floatx16 __attribute__((ext_vector_type(16)));

#define TT 20
#define NB 64      // batch per step
#define LL 90
#define DD 64
#define RR 5760    // L*D
#define HH 1024
#define NG 4096    // 4*H
#define KT 6784    // RR + HH
#define CH0 90     // chunks in K-part0 (5760/64)
#define CHT 106    // total 64-half chunks (6784/64)

__device__ __forceinline__ float sigm(float x) { return 1.f / (1.f + expf(-x)); }

// ---------------- fp32 -> fp16 convert ----------------
__global__ __launch_bounds__(256) void k_conv(const float* __restrict__ s,
                                              _Float16* __restrict__ d, int n) {
    int i = (blockIdx.x * 256 + threadIdx.x) * 4;
    if (i + 4 <= n) {
        const float4 v = *(const float4*)(s + i);
        half4v o;
        o[0] = (_Float16)v.x; o[1] = (_Float16)v.y;
        o[2] = (_Float16)v.z; o[3] = (_Float16)v.w;
        *(half4v*)(d + i) = o;
    } else {
        for (; i < n; ++i) d[i] = (_Float16)s[i];
    }
}

// ---------------- xproj = feature @ attn_Wx  -> fp16 [1280][90][64] ----------------
__global__ __launch_bounds__(256) void k_xproj(const float* __restrict__ feat,
                                               const float* __restrict__ Wx,
                                               _Float16* __restrict__ xp) {
    __shared__ float sWx[DD * DD];
    __shared__ float sx[16 * DD];
    const int row = blockIdx.x;            // 0..1279  (= b*TT + t)
    const int tid = threadIdx.x;
    for (int e = tid * 4; e < DD * DD; e += 1024)
        *(float4*)(sWx + e) = *(const float4*)(Wx + e);
    const int a4 = tid & 15, lg = tid >> 4;
    const float* frow = feat + (size_t)row * RR;
    for (int lb = 0; lb < LL; lb += 16) {
        __syncthreads();
        { int e = tid * 4; int ls = e >> 6, dd = e & 63;
          if (lb + ls < LL) *(float4*)(sx + e) = *(const float4*)(frow + (lb + ls) * DD + dd); }
        __syncthreads();
        const int l = lb + lg;
        if (l < LL) {
            float a0 = 0, a1 = 0, a2 = 0, a3 = 0;
            for (int dd = 0; dd < DD; ++dd) {
                const float xv = sx[lg * DD + dd];
                const float4 wv = *(const float4*)(sWx + dd * DD + a4 * 4);
                a0 += xv * wv.x; a1 += xv * wv.y; a2 += xv * wv.z; a3 += xv * wv.w;
            }
            half4v o;
            o[0] = (_Float16)a0; o[1] = (_Float16)a1; o[2] = (_Float16)a2; o[3] = (_Float16)a3;
            *(half4v*)(xp + (size_t)row * RR + l * DD + a4 * 4) = o;
        }
    }
}

// ---------------- init h0, c0 ----------------
__global__ __launch_bounds__(256) void k_init(const float* __restrict__ feat,
        const float* __restrict__ iWh_w, const float* __restrict__ iWh_b,
        const float* __restrict__ iWc_w, const float* __restrict__ iWc_b,
        float* __restrict__ h, float* __restrict__ c, _Float16* __restrict__ h16) {
    __shared__ float f0p[4][DD];
    __shared__ float f0[DD];
    const int b = blockIdx.x, tid = threadIdx.x;
    const int dd = tid & 63, lg = tid >> 6;
    const float* frow = feat + (size_t)(b * TT) * RR;   // t = 0
    float p = 0;
    for (int l = lg; l < LL; l += 4) p += frow[l * DD + dd];
    f0p[lg][dd] = p;
    __syncthreads();
    if (tid < DD) f0[tid] = (f0p[0][tid] + f0p[1][tid] + f0p[2][tid] + f0p[3][tid]) * (1.0f / LL);
    __syncthreads();
    for (int o = tid; o < HH; o += 256) {
        float ah = iWh_b[o], ac = iWc_b[o];
        for (int d0 = 0; d0 < DD; d0 += 4) {
            const float4 wh = *(const float4*)(iWh_w + (size_t)o * DD + d0);
            const float4 wc = *(const float4*)(iWc_w + (size_t)o * DD + d0);
            ah += f0[d0] * wh.x + f0[d0 + 1] * wh.y + f0[d0 + 2] * wh.z + f0[d0 + 3] * wh.w;
            ac += f0[d0] * wc.x + f0[d0 + 1] * wc.y + f0[d0 + 2] * wc.z + f0[d0 + 3] * wc.w;
        }
        const float hv = tanhf(ah), cv = tanhf(ac);
        h[b * HH + o] = hv; c[b * HH + o] = cv;
        h16[b * HH + o] = (_Float16)hv;
    }
}

// ===== fused LSTM cell (step tattn-1, if do_cell) + attention for step tattn =====
// 64 blocks (one per batch b) x 512 threads.
__global__ __launch_bounds__(512) void k_step(int tattn, int do_cell,
        const float* __restrict__ gpart, const float* __restrict__ b_ih,
        const float* __restrict__ b_hh, float* __restrict__ cbuf,
        _Float16* __restrict__ h16, _Float16* __restrict__ H16,
        const float* __restrict__ h0buf,
        const float* __restrict__ feat, const _Float16* __restrict__ xp,
        const float* __restrict__ Wh, const float* __restrict__ v,
        _Float16* __restrict__ V16) {
    __shared__ float sh[HH];
    __shared__ float hWhp[8][DD];
    __shared__ float hWh[DD];
    __shared__ float sv[DD];
    __shared__ float ep[LL][4];
    __shared__ float se[128];
    __shared__ float salpha[LL];
    __shared__ float red[128];
    const int b = blockIdx.x, tid = threadIdx.x;
    if (tid < DD) sv[tid] = v[tid];

    if (do_cell) {
        // ----- cell for step tattn-1: 2 hidden units per thread -----
        const int j0 = tid * 2;
        float ag[4][2];
#pragma unroll
        for (int g = 0; g < 4; ++g) { ag[g][0] = 0.f; ag[g][1] = 0.f; }
#pragma unroll
        for (int sp = 0; sp < 4; ++sp) {
            const float* P = gpart + ((size_t)sp * NB + b) * NG;
#pragma unroll
            for (int g = 0; g < 4; ++g) {
                const float2 pv = *(const float2*)(P + g * HH + j0);
                ag[g][0] += pv.x; ag[g][1] += pv.y;
            }
        }
#pragma unroll
        for (int g = 0; g < 4; ++g) {
            const float2 bi = *(const float2*)(b_ih + g * HH + j0);
            const float2 bh = *(const float2*)(b_hh + g * HH + j0);
            ag[g][0] += bi.x + bh.x; ag[g][1] += bi.y + bh.y;
        }
        const float2 cold = *(const float2*)(cbuf + (size_t)b * HH + j0);
        float co[2] = { cold.x, cold.y };
        float2 cnew; half2v hh2;
#pragma unroll
        for (int q = 0; q < 2; ++q) {
            const float cv = sigm(ag[1][q]) * co[q] + sigm(ag[0][q]) * tanhf(ag[2][q]);
            const float hv = sigm(ag[3][q]) * tanhf(cv);
            ((float*)&cnew)[q] = cv;
            hh2[q] = (_Float16)hv;
            sh[j0 + q] = hv;
        }
        *(float2*)(cbuf + (size_t)b * HH + j0) = cnew;
        *(half2v*)(h16 + (size_t)b * HH + j0) = hh2;
        *(half2v*)(H16 + ((size_t)(tattn - 1) * NB + b) * HH + j0) = hh2;
    } else {
        for (int e = tid; e < HH; e += 512) sh[e] = h0buf[b * HH + e];
    }
    __syncthreads();
    if (tattn >= TT) return;

    // ----- hWh = h @ Wh : 8-way K-split, coalesced 256B wave loads -----
    { const int a = tid & 63, q = tid >> 6;           // q in 0..7
      const float* Wq = Wh + (size_t)(q * 128) * DD + a;
      const float* shq = sh + q * 128;
      float p0 = 0.f, p1 = 0.f;
#pragma unroll 8
      for (int k = 0; k < 128; k += 2) {
          p0 += shq[k] * Wq[(size_t)k * DD];
          p1 += shq[k + 1] * Wq[(size_t)(k + 1) * DD];
      }
      hWhp[q][a] = p0 + p1; }
    __syncthreads();
    if (tid < DD) {
        float s = 0.f;
#pragma unroll
        for (int q = 0; q < 8; ++q) s += hWhp[q][tid];
        hWh[tid] = s;
    }
    __syncthreads();

    // ----- e_l = sum_d tanh(xp + hWh) * v : 360 tasks (l, quarter) -----
    const size_t frow = (size_t)(b * TT + tattn) * RR;
    if (tid < 360) {
        const int l = tid >> 2, qq = tid & 3;
        const _Float16* xr = xp + frow + l * DD + qq * 16;
        const half8 x0 = *(const half8*)(xr);
        const half8 x1 = *(const half8*)(xr + 8);
        float acc = 0.f;
#pragma unroll
        for (int i = 0; i < 8; ++i)
            acc += tanhf((float)x0[i] + hWh[qq * 16 + i]) * sv[qq * 16 + i];
#pragma unroll
        for (int i = 0; i < 8; ++i)
            acc += tanhf((float)x1[i] + hWh[qq * 16 + 8 + i]) * sv[qq * 16 + 8 + i];
        ep[l][qq] = acc;
    }
    __syncthreads();
    if (tid < LL) se[tid] = ep[tid][0] + ep[tid][1] + ep[tid][2] + ep[tid][3];
    else if (tid < 128) se[tid] = -1e30f;
    __syncthreads();
    if (tid < 128) red[tid] = se[tid];
    __syncthreads();
    for (int s = 64; s; s >>= 1) { if (tid < s) red[tid] = fmaxf(red[tid], red[tid + s]); __syncthreads(); }
    const float mx = red[0];
    __syncthreads();
    float ex = 0.f;
    if (tid < LL) { ex = expf(se[tid] - mx); salpha[tid] = ex; }
    if (tid < 128) red[tid] = ex;
    __syncthreads();
    for (int s = 64; s; s >>= 1) { if (tid < s) red[tid] += red[tid + s]; __syncthreads(); }
    const float inv = 1.f / red[0];
    __syncthreads();
    if (tid < LL) salpha[tid] *= inv;
    __syncthreads();

    // ----- visual write: vectorized -----
    _Float16* vout = V16 + ((size_t)tattn * NB + b) * RR;
    const float* fr = feat + frow;
    for (int e = tid * 4; e < RR; e += 2048) {
        const float4 u = *(const float4*)(fr + e);
        const float al = salpha[e >> 6];
        half4v o;
        o[0] = (_Float16)(u.x * al); o[1] = (_Float16)(u.y * al);
        o[2] = (_Float16)(u.z * al); o[3] = (_Float16)(u.w * al);
        *(half4v*)(vout + e) = o;
    }
}

// ================= tiled GEMM machinery (gates) =================
__device__ __forceinline__ void stage_tile(const char* src, size_t stride, char* lds, int ln) {
    const char* g = src + (size_t)(ln >> 3) * stride + (((ln & 7) ^ (ln >> 3)) << 4);
#pragma unroll
    for (int i = 0; i < 8; ++i)
        __builtin_amdgcn_global_load_lds(
            (const __attribute__((address_space(1))) void*)(g + (size_t)(i * 8) * stride),
            (__attribute__((address_space(3))) void*)(lds + i * 1024), 16, 0, 0);
}

struct Src2 { const char* p0; size_t s0; const char* p1; size_t s1; };

__device__ __forceinline__ const char* chunk_ptr(const Src2& s, int c, size_t& stride) {
    if (c < CH0) { stride = s.s0; return s.p0 + (size_t)c * 128; }
    stride = s.s1; return s.p1 + (size_t)(c - CH0) * 128;
}

template<int NT, int SB>
__global__ __launch_bounds__(128) void k_gemm(
        const _Float16* __restrict__ A0, const _Float16* __restrict__ A1,
        const _Float16* __restrict__ B0, const _Float16* __restrict__ B1,
        float* __restrict__ C, int ldc, size_t part_elems) {
    __shared__ char smem[65536];
    const int bid = blockIdx.x;
    const int kb = bid % SB;
    const int nt = (bid / SB) % NT;
    const int mt = bid / (SB * NT);
    const int tid = threadIdx.x, w = tid >> 6, ln = tid & 63;
    char* wlds = smem + w * 32768;

    const int arow = mt * 64, brow = nt * 64;
    Src2 As = { (const char*)(A0 + (size_t)arow * RR), (size_t)RR * 2,
                (const char*)(A1 + (size_t)arow * HH), (size_t)HH * 2 };
    Src2 Bs = { (const char*)(B0 + (size_t)brow * RR), (size_t)RR * 2,
                (const char*)(B1 + (size_t)brow * HH), (size_t)HH * 2 };

    floatx16 acc00, acc01, acc10, acc11;
#pragma unroll
    for (int i = 0; i < 16; ++i) { acc00[i] = 0.f; acc01[i] = 0.f; acc10[i] = 0.f; acc11[i] = 0.f; }

    const int start = kb * 2 + w;
    const int STRIDE = SB * 2;
    const int r = ln & 31;
    const int xsw = (r & 7) << 4;
    const int fo = (ln >> 5) * 16;
    const int rbyte = r * 128;

    int c = start, bsel = 0;
    { size_t st; const char* p = chunk_ptr(As, c, st); stage_tile(p, st, wlds, ln);
      p = chunk_ptr(Bs, c, st); stage_tile(p, st, wlds + 8192, ln); }
    while (true) {
        const int cn = c + STRIDE;
        if (cn < CHT) {
            char* nl = wlds + ((bsel ^ 1) << 14);
            size_t st; const char* p = chunk_ptr(As, cn, st); stage_tile(p, st, nl, ln);
            p = chunk_ptr(Bs, cn, st); stage_tile(p, st, nl + 8192, ln);
            asm volatile("s_waitcnt vmcnt(16)" ::: "memory");
        } else {
            asm volatile("s_waitcnt vmcnt(0)" ::: "memory");
        }
        __builtin_amdgcn_sched_barrier(0);
        const char* LA = wlds + (bsel << 14);
        const char* LB = LA + 8192;
#pragma unroll
        for (int kk = 0; kk < 4; ++kk) {
            const int o = ((kk * 32 + fo) ^ xsw);
            const half8 a0 = *(const half8*)(LA + rbyte + o);
            const half8 a1 = *(const half8*)(LA + 4096 + rbyte + o);
            const half8 b0 = *(const half8*)(LB + rbyte + o);
            const half8 b1 = *(const half8*)(LB + 4096 + rbyte + o);
            acc00 = __builtin_amdgcn_mfma_f32_32x32x16_f16(a0, b0, acc00, 0, 0, 0);
            acc01 = __builtin_amdgcn_mfma_f32_32x32x16_f16(a0, b1, acc01, 0, 0, 0);
            acc10 = __builtin_amdgcn_mfma_f32_32x32x16_f16(a1, b0, acc10, 0, 0, 0);
            acc11 = __builtin_amdgcn_mfma_f32_32x32x16_f16(a1, b1, acc11, 0, 0, 0);
        }
        if (cn >= CHT) break;
        c = cn; bsel ^= 1;
    }
    __syncthreads();
    float* Rg = (float*)(smem + w * 16384);
    const int rbase = 4 * (ln >> 5), lr = ln & 31;
#pragma unroll
    for (int q = 0; q < 16; ++q) {
        const int row = rbase + (q & 3) + 8 * (q >> 2);
        Rg[row * 64 + lr]             = acc00[q];
        Rg[row * 64 + 32 + lr]        = acc01[q];
        Rg[(row + 32) * 64 + lr]      = acc10[q];
        Rg[(row + 32) * 64 + 32 + lr] = acc11[q];
    }
    __syncthreads();
    const float* R0 = (const float*)smem;
    const float* R1 = (const float*)(smem + 16384);
    float* Cout = C + (size_t)kb * part_elems;
    for (int e = tid * 4; e < 4096; e += 512) {
        const float4 u = *(const float4*)(R0 + e);
        const float4 v2 = *(const float4*)(R1 + e);
        float4 s2; s2.x = u.x + v2.x; s2.y = u.y + v2.y; s2.z = u.z + v2.z; s2.w = u.w + v2.w;
        const int row = e >> 6, col = e & 63;
        *(float4*)(Cout + (size_t)(arow + row) * ldc + brow + col) = s2;
    }
}

// ===== Wu-fused head weights: Wyu16[j][0:6784] = Wu @ [Wy | Whw], cst[j] =====
__global__ __launch_bounds__(256) void k_wfuse(const float* __restrict__ Wy,
        const float* __restrict__ Whw, const float* __restrict__ Wu,
        const float* __restrict__ Whb, const float* __restrict__ Wub,
        _Float16* __restrict__ Wyu16, float* __restrict__ cst) {
    __shared__ float sWu[3 * HH];
    __shared__ float part[4][3][64];
    const int tid = threadIdx.x;
    for (int e = tid * 4; e < 3 * HH; e += 1024)
        *(float4*)(sWu + e) = *(const float4*)(Wu + e);
    __syncthreads();
    if (blockIdx.x == CHT) {   // cst block
        float a0 = 0, a1 = 0, a2 = 0;
        for (int m = tid; m < HH; m += 256) {
            const float wb = Whb[m];
            a0 += sWu[m] * wb; a1 += sWu[HH + m] * wb; a2 += sWu[2 * HH + m] * wb;
        }
        __shared__ float rp[3][256];
        rp[0][tid] = a0; rp[1][tid] = a1; rp[2][tid] = a2;
        __syncthreads();
        for (int s = 128; s; s >>= 1) {
            if (tid < s) { rp[0][tid] += rp[0][tid + s]; rp[1][tid] += rp[1][tid + s]; rp[2][tid] += rp[2][tid + s]; }
            __syncthreads();
        }
        if (tid < 3) cst[tid] = rp[tid][0] + Wub[tid];
        return;
    }
    const int kk = tid & 63, qm = tid >> 6;
    const int k = blockIdx.x * 64 + kk;
    const float* src; size_t ld;
    if (blockIdx.x < CH0) { src = Wy + k; ld = RR; }
    else { src = Whw + (k - RR); ld = HH; }
    float a0 = 0, a1 = 0, a2 = 0;
    for (int m = qm * 256; m < qm * 256 + 256; ++m) {
        const float val = src[(size_t)m * ld];
        a0 += sWu[m] * val; a1 += sWu[HH + m] * val; a2 += sWu[2 * HH + m] * val;
    }
    part[qm][0][kk] = a0; part[qm][1][kk] = a1; part[qm][2][kk] = a2;
    __syncthreads();
    if (tid < 192) {
        const int j = tid >> 6, k2 = tid & 63;
        const float s = part[0][j][k2] + part[1][j][k2] + part[2][j][k2] + part[3][j][k2];
        Wyu16[(size_t)j * KT + blockIdx.x * 64 + k2] = (_Float16)s;
    }
}

// ===== final: out[r][j] = V16[r].Wyu[j][:5760] + H16[r].Wyu[j][5760:] + cst[j] =====
__global__ __launch_bounds__(256) void k_final2(const _Float16* __restrict__ V16,
        const _Float16* __restrict__ H16, const _Float16* __restrict__ Wyu,
        const float* __restrict__ cst, float* __restrict__ out) {
    __shared__ float rp[4][3];
    const int r = blockIdx.x, tid = threadIdx.x;   // r = t*64 + b
    const _Float16* vrow = V16 + (size_t)r * RR;
    const _Float16* hrow = H16 + (size_t)r * HH;
    float a0 = 0, a1 = 0, a2 = 0;
    for (int e = tid * 8; e < KT; e += 2048) {
        half8 x;
        if (e < RR) x = *(const half8*)(vrow + e);
        else        x = *(const half8*)(hrow + (e - RR));
        const half8 w0 = *(const half8*)(Wyu + e);
        const half8 w1 = *(const half8*)(Wyu + KT + e);
        const half8 w2 = *(const half8*)(Wyu + 2 * KT + e);
#pragma unroll
        for (int i = 0; i < 8; ++i) {
            const float xv = (float)x[i];
            a0 += xv * (float)w0[i]; a1 += xv * (float)w1[i]; a2 += xv * (float)w2[i];
        }
    }
    for (int o = 32; o > 0; o >>= 1) {
        a0 += __shfl_down(a0, o, 64); a1 += __shfl_down(a1, o, 64); a2 += __shfl_down(a2, o, 64);
    }
    const int wv = tid >> 6;
    if ((tid & 63) == 0) { rp[wv][0] = a0; rp[wv][1] = a1; rp[wv][2] = a2; }
    __syncthreads();
    if (tid < 3) {
        const float x = rp[0][tid] + rp[1][tid] + rp[2][tid] + rp[3][tid] + cst[tid];
        const int b = r & 63, ts = r >> 6;
        out[((size_t)b * TT + ts) * 3 + tid] = x;
    }
}

extern "C" void kernel_launch(void* const* d_in, const int* in_sizes, int n_in,
                              void* d_out, int out_size, void* d_ws, size_t ws_size,
                              hipStream_t stream) {
    (void)in_sizes; (void)n_in; (void)out_size;
    const float* feature = (const float*)d_in[0];
    const float* attn_Wx = (const float*)d_in[1];
    const float* attn_Wh = (const float*)d_in[2];
    const float* attn_v  = (const float*)d_in[3];
    const float* W_ih    = (const float*)d_in[4];
    const float* W_hh    = (const float*)d_in[5];
    const float* b_ih    = (const float*)d_in[6];
    const float* b_hh    = (const float*)d_in[7];
    const float* Wh_w    = (const float*)d_in[8];
    const float* Wh_b    = (const float*)d_in[9];
    const float* Wy_w    = (const float*)d_in[10];
    const float* Wu_w    = (const float*)d_in[11];
    const float* Wu_b    = (const float*)d_in[12];
    const float* iWh_w   = (const float*)d_in[13];
    const float* iWh_b   = (const float*)d_in[14];
    const float* iWc_w   = (const float*)d_in[15];
    const float* iWc_b   = (const float*)d_in[16];
    float* out = (float*)d_out;

    char* ws = (char*)d_ws;
    size_t off = 0;
    auto alloc = [&](size_t bytes) { void* p = ws + off; off += (bytes + 255) & ~(size_t)255; return p; };
    _Float16* Wih16 = (_Float16*)alloc((size_t)NG * RR * 2);
    _Float16* Whh16 = (_Float16*)alloc((size_t)NG * HH * 2);
    _Float16* xp16  = (_Float16*)alloc((size_t)1280 * RR * 2);
    _Float16* V16   = (_Float16*)alloc((size_t)TT * NB * RR * 2);
    _Float16* H16   = (_Float16*)alloc((size_t)TT * NB * HH * 2);
    float*    hbuf  = (float*)alloc((size_t)NB * HH * 4);
    float*    cbuf  = (float*)alloc((size_t)NB * HH * 4);
    _Float16* h16   = (_Float16*)alloc((size_t)NB * HH * 2);
    float*    gpart = (float*)alloc((size_t)4 * NB * NG * 4);
    _Float16* Wyu16 = (_Float16*)alloc((size_t)3 * KT * 2);
    float*    cstb  = (float*)alloc(16);
    if (ws_size < off) return;   // refuse to scribble out of bounds

    // one-time: weight conversions + xproj + head-weight fusion + init + attn(0)
    k_conv<<<(NG * RR / 4 + 255) / 256, 256, 0, stream>>>(W_ih, Wih16, NG * RR);
    k_conv<<<(NG * HH / 4 + 255) / 256, 256, 0, stream>>>(W_hh, Whh16, NG * HH);
    k_xproj<<<1280, 256, 0, stream>>>(feature, attn_Wx, xp16);
    k_wfuse<<<CHT + 1, 256, 0, stream>>>(Wy_w, Wh_w, Wu_w, Wh_b, Wu_b, Wyu16, cstb);
    k_init<<<64, 256, 0, stream>>>(feature, iWh_w, iWh_b, iWc_w, iWc_b, hbuf, cbuf, h16);
    k_step<<<64, 512, 0, stream>>>(0, 0, gpart, b_ih, b_hh, cbuf, h16, H16, hbuf,
                                   feature, xp16, attn_Wh, attn_v, V16);

    for (int t = 0; t < TT; ++t) {
        const _Float16* Vt = V16 + (size_t)t * NB * RR;
        k_gemm<64, 4><<<256, 128, 0, stream>>>(Vt, h16, Wih16, Whh16,
                                               gpart, NG, (size_t)NB * NG);
        k_step<<<64, 512, 0, stream>>>(t + 1, 1, gpart, b_ih, b_hh, cbuf, h16, H16, hbuf,
                                       feature, xp16, attn_Wh, attn_v, V16);
    }

    k_final2<<<1280, 256, 0, stream>>>(V16, H16, Wyu16, cstb, out);
}